// Round 14
// baseline (1787.276 us; speedup 1.0000x reference)
//
#include <hip/hip_runtime.h>
#include <math.h>

#define NN 2048
#define EE 65536
#define T_OBS 6
#define FIN 2
#define HE 256
#define LT 128
#define XC 384          // xcat width: [zlat(128) | h_dec(256)]
#define PREDN 6
#define DMM_NZ 4
#define GT_NZ 4
#define LIN_NZ 8

typedef __attribute__((ext_vector_type(8))) short short8v;
typedef __attribute__((ext_vector_type(4))) short short4v;
typedef __attribute__((ext_vector_type(4))) float float4v;

static __device__ __forceinline__ unsigned short f2bf(float f) {
    union { float f; unsigned u; } v; v.f = f;
    unsigned r = v.u + 0x7fff + ((v.u >> 16) & 1);
    return (unsigned short)(r >> 16);
}

static __device__ __forceinline__ void bfsplit(float f, unsigned short& h,
                                               unsigned short& l) {
    unsigned u = __float_as_uint(f);
    h = (unsigned short)(u >> 16);
    float hf = __uint_as_float(u & 0xffff0000u);
    l = (unsigned short)(__float_as_uint(f - hf) >> 16);
}

static __device__ __forceinline__ float bf2f(unsigned short b) {
    return __uint_as_float(((unsigned)b) << 16);
}

// ---------------- batched sparse graph prep ----------------
__global__ void k_degcnt_lds(const int* __restrict__ ei, const float* __restrict__ ews,
                             float* __restrict__ deg_all, int* __restrict__ cnt_all) {
    __shared__ float ldeg[NN];
    __shared__ int lcnt[NN];
    int tg = blockIdx.y;
    const int* src = ei + (size_t)tg * 2 * EE;
    const int* dst = src + EE;
    const float* ew = ews + (size_t)tg * EE;
    for (int i = threadIdx.x; i < NN; i += 256) { ldeg[i] = 0.f; lcnt[i] = 0; }
    __syncthreads();
    const int EPB = EE / 8;
    int e0 = blockIdx.x * EPB;
    for (int e = e0 + threadIdx.x; e < e0 + EPB; e += 256) {
        atomicAdd(&ldeg[src[e]], ew[e]);
        atomicAdd(&lcnt[dst[e]], 1);
    }
    __syncthreads();
    for (int i = threadIdx.x; i < NN; i += 256) {
        float d = ldeg[i]; int cc = lcnt[i];
        if (d != 0.f) atomicAdd(&deg_all[tg * NN + i], d);
        if (cc) atomicAdd(&cnt_all[tg * NN + i], cc);
    }
}

__global__ void k_scan_b(const int* __restrict__ cnt_all, const float* __restrict__ deg_all,
                         int* __restrict__ roff_all, int* __restrict__ cur_all,
                         float* __restrict__ dinv_all) {
    __shared__ int part[256];
    int tg = blockIdx.x;
    const int* cnt = cnt_all + tg * NN;
    const float* deg = deg_all + tg * NN;
    int* roff = roff_all + tg * (NN + 1);
    int* cur = cur_all + tg * NN;
    float* dinv = dinv_all + tg * NN;
    int t = threadIdx.x;
#pragma unroll
    for (int i = t; i < NN; i += 256) {
        float d = deg[i];
        dinv[i] = d > 0.f ? 1.f / sqrtf(d) : 0.f;
    }
    int loc[8];
    int s = 0;
#pragma unroll
    for (int i = 0; i < 8; i++) { loc[i] = cnt[t * 8 + i]; s += loc[i]; }
    part[t] = s;
    __syncthreads();
    for (int off = 1; off < 256; off <<= 1) {
        int v = (t >= off) ? part[t - off] : 0;
        __syncthreads();
        part[t] += v;
        __syncthreads();
    }
    int run = (t == 0) ? 0 : part[t - 1];
#pragma unroll
    for (int i = 0; i < 8; i++) {
        int idx = t * 8 + i;
        roff[idx] = run;
        cur[idx] = run;
        run += loc[i];
    }
    if (t == 255) roff[NN] = run;
}

__global__ void k_scatter2_b(const int* __restrict__ ei, const float* __restrict__ ews,
                             const float* __restrict__ dinv_all, int* __restrict__ cur_all,
                             int* __restrict__ csr_src_all, float* __restrict__ csr_nrm_all) {
    int tg = blockIdx.y;
    int e = blockIdx.x * blockDim.x + threadIdx.x;
    const int* src = ei + (size_t)tg * 2 * EE;
    const int* dst = src + EE;
    const float* ew = ews + (size_t)tg * EE;
    const float* dinv = dinv_all + tg * NN;
    if (e < EE) {
        int s = src[e], d = dst[e];
        int p = atomicAdd(&cur_all[tg * NN + d], 1);
        csr_src_all[(size_t)tg * EE + p] = s;
        csr_nrm_all[(size_t)tg * EE + p] = -dinv[s] * ew[e] * dinv[d];
    }
}

__global__ void k_spmm2_b(const int* __restrict__ roff_all, const int* __restrict__ csr_src_all,
                          const float* __restrict__ csr_nrm_all, const float* __restrict__ x_seq,
                          float* __restrict__ aggx_all) {
    int tg = blockIdx.y;
    int nid = blockIdx.x * blockDim.x + threadIdx.x;
    if (nid < NN) {
        const int* roff = roff_all + tg * (NN + 1);
        const int* csr_src = csr_src_all + (size_t)tg * EE;
        const float* csr_nrm = csr_nrm_all + (size_t)tg * EE;
        const float* X = x_seq + (size_t)tg * NN * FIN;
        int s0 = roff[nid], s1 = roff[nid + 1];
        float a0 = 0.f, a1 = 0.f;
        for (int s = s0; s < s1; ++s) {
            int i = csr_src[s]; float w = csr_nrm[s];
            float2 xv = *(const float2*)&X[2 * i];
            a0 = fmaf(w, xv.x, a0);
            a1 = fmaf(w, xv.y, a1);
        }
        aggx_all[(size_t)tg * NN * FIN + 2 * nid] = a0;
        aggx_all[(size_t)tg * NN * FIN + 2 * nid + 1] = a1;
    }
}

// CSR SpMM gathering bf16 X; TPN threads per node; out stride ldo
template <int F, int TPN>
__global__ void k_spmm_vb(const int* __restrict__ roff, const int* __restrict__ csr_src,
                          const float* __restrict__ csr_nrm,
                          const unsigned short* __restrict__ Xb,
                          float* __restrict__ out, int ldo) {
    const int NPB = 256 / TPN;
    int w = threadIdx.x / TPN, l = threadIdx.x % TPN;
    int nid = blockIdx.x * NPB + w;
    int c = l << 2;
    int s0 = roff[nid], s1 = roff[nid + 1];
    float4 acc = make_float4(0.f, 0.f, 0.f, 0.f);
    int s = s0;
    for (; s + 8 <= s1; s += 8) {
        int is[8]; float ws[8];
#pragma unroll
        for (int j = 0; j < 8; j++) { is[j] = csr_src[s + j]; ws[j] = csr_nrm[s + j]; }
        if (c < F) {
            short4v xv[8];
#pragma unroll
            for (int j = 0; j < 8; j++)
                xv[j] = *(const short4v*)&Xb[(size_t)is[j] * F + c];
#pragma unroll
            for (int j = 0; j < 8; j++) {
                acc.x = fmaf(ws[j], bf2f((unsigned short)xv[j][0]), acc.x);
                acc.y = fmaf(ws[j], bf2f((unsigned short)xv[j][1]), acc.y);
                acc.z = fmaf(ws[j], bf2f((unsigned short)xv[j][2]), acc.z);
                acc.w = fmaf(ws[j], bf2f((unsigned short)xv[j][3]), acc.w);
            }
        }
    }
    for (; s < s1; ++s) {
        int i0 = csr_src[s]; float w0 = csr_nrm[s];
        if (c < F) {
            short4v xv = *(const short4v*)&Xb[(size_t)i0 * F + c];
            acc.x = fmaf(w0, bf2f((unsigned short)xv[0]), acc.x);
            acc.y = fmaf(w0, bf2f((unsigned short)xv[1]), acc.y);
            acc.z = fmaf(w0, bf2f((unsigned short)xv[2]), acc.z);
            acc.w = fmaf(w0, bf2f((unsigned short)xv[3]), acc.w);
        }
    }
    if (c < F) *(float4*)&out[(size_t)nid * ldo + c] = acc;
}

// ---------------- dense graph prep (rollout) ----------------
__global__ void k_ddeg(const float* __restrict__ c, float* __restrict__ dinv) {
    int i = blockIdx.x;
    int t = threadIdx.x;
    float xi = c[2 * i], yi = c[2 * i + 1];
    float s = 0.f;
    for (int j = t; j < NN; j += 256) {
        float dx = xi - c[2 * j], dy = yi - c[2 * j + 1];
        float d = sqrtf(dx * dx + dy * dy);
        if (d > 0.f && d < 0.5f) s += 2.f * d;
    }
    __shared__ float red[256];
    red[t] = s;
    __syncthreads();
    for (int off = 128; off > 0; off >>= 1) {
        if (t < off) red[t] += red[t + off];
        __syncthreads();
    }
    if (t == 0) {
        float d = red[0];
        dinv[i] = d > 0.f ? 1.f / sqrtf(d) : 0.f;
    }
}

// fused: bf16 M row + encoder F=2 aggregation (M @ yhat)
__global__ void k_dM2(const float* __restrict__ c, const float* __restrict__ dinv,
                      unsigned short* __restrict__ Mb, float* __restrict__ ax) {
    int i = blockIdx.x;
    int t = threadIdx.x;
    float xi = c[2 * i], yi = c[2 * i + 1], di = dinv[i];
    float a0 = 0.f, a1 = 0.f;
    for (int j = t; j < NN; j += 256) {
        float dx = xi - c[2 * j], dy = yi - c[2 * j + 1];
        float d = sqrtf(dx * dx + dy * dy);
        float w = (d > 0.f && d < 0.5f) ? 2.f * d : 0.f;
        float v = -(di * w) * dinv[j];
        Mb[(size_t)i * NN + j] = f2bf(v);
        a0 = fmaf(v, c[2 * j], a0);
        a1 = fmaf(v, c[2 * j + 1], a1);
    }
    __shared__ float r0[256], r1[256];
    r0[t] = a0;
    r1[t] = a1;
    __syncthreads();
    for (int off = 128; off > 0; off >>= 1) {
        if (t < off) { r0[t] += r0[t + off]; r1[t] += r1[t + off]; }
        __syncthreads();
    }
    if (t == 0) { ax[2 * i] = r0[0]; ax[2 * i + 1] = r1[0]; }
}

// dense agg via bf16 MFMA, X already bf16 (row-major [NN][F])
template <int F>
__global__ __launch_bounds__(256) void k_dmm_mfb(
    const unsigned short* __restrict__ Mb, const unsigned short* __restrict__ Xb,
    float* __restrict__ pbuf)
{
    __shared__ __align__(16) unsigned short Ms[64][72];
    __shared__ __align__(16) unsigned short Xs[64][72];
    const int tid = threadIdx.x;
    const int wid = tid >> 6, lane = tid & 63;
    const int m0 = blockIdx.x << 6, n0 = blockIdx.y << 6;
    const int kchunk = NN / DMM_NZ;
    const int kb0 = blockIdx.z * kchunk;
    const int lr = lane & 15;
    const int kg = lane >> 4;
    float4v acc[4];
#pragma unroll
    for (int t = 0; t < 4; t++) acc[t] = (float4v){0.f, 0.f, 0.f, 0.f};

    for (int kb = kb0; kb < kb0 + kchunk; kb += 64) {
#pragma unroll
        for (int it = 0; it < 2; it++) {
            int i = tid + it * 256;
            int r = i >> 3, c8 = (i & 7) << 3;
            *(short8v*)&Ms[r][c8] =
                *(const short8v*)&Mb[(size_t)(m0 + r) * NN + kb + c8];
        }
#pragma unroll
        for (int it = 0; it < 2; it++) {
            int i = tid + it * 256;
            int k2 = (i & 31) << 1;
            int n4 = (i >> 5) << 2;
            short4v va = *(const short4v*)&Xb[(size_t)(kb + k2) * F + n0 + n4];
            short4v vb = *(const short4v*)&Xb[(size_t)(kb + k2 + 1) * F + n0 + n4];
#pragma unroll
            for (int j = 0; j < 4; j++)
                *(unsigned*)&Xs[n4 + j][k2] =
                    (unsigned)(unsigned short)va[j] |
                    ((unsigned)(unsigned short)vb[j] << 16);
        }
        __syncthreads();
#pragma unroll
        for (int kh = 0; kh < 2; kh++) {
            int kk = kh * 32 + kg * 8;
            short8v a = *(const short8v*)&Ms[(wid << 4) + lr][kk];
#pragma unroll
            for (int t = 0; t < 4; t++) {
                short8v b = *(const short8v*)&Xs[(t << 4) + lr][kk];
                acc[t] = __builtin_amdgcn_mfma_f32_16x16x32_bf16(a, b, acc[t], 0, 0, 0);
            }
        }
        __syncthreads();
    }
    float* p = pbuf + (size_t)blockIdx.z * NN * F;
#pragma unroll
    for (int t = 0; t < 4; t++)
#pragma unroll
        for (int j = 0; j < 4; j++)
            p[(size_t)(m0 + (wid << 4) + (kg << 2) + j) * F + n0 + (t << 4) + lr] =
                acc[t][j];
}

template <int F, int NZ>
__global__ void k_redks(const float* __restrict__ pbuf, float* __restrict__ out) {
    const int TOT = NN * F / 4;
    int i = blockIdx.x * blockDim.x + threadIdx.x;
    if (i < TOT) {
        const float4* p = (const float4*)pbuf;
        float4 s = p[i];
#pragma unroll
        for (int z = 1; z < NZ; z++) {
            float4 v = p[(size_t)z * TOT + i];
            s.x += v.x; s.y += v.y; s.z += v.z; s.w += v.w;
        }
        ((float4*)out)[i] = s;
    }
}

// ---------------- bf16x3 MFMA GEMM segment core (r8 proven) ----------------
template <bool RELU>
__device__ __forceinline__ void mfma_seg(
    unsigned short (*Ah)[40], unsigned short (*Al)[40],
    unsigned short (*Bh)[40], unsigned short (*Bl)[40],
    const float* __restrict__ A, int lda,
    const float* __restrict__ B, int ldb, int K,
    int m0, int tid, int wid, int lr, int kg, float4v (&acc)[4])
{
    for (int k0 = 0; k0 < K; k0 += 32) {
        {
            int r = tid >> 2, k8 = (tid & 3) << 3;
            const float* ap = &A[(size_t)(m0 + r) * lda + k0 + k8];
            float4 va = *(const float4*)ap;
            float4 vb = *(const float4*)(ap + 4);
            float v[8] = {va.x, va.y, va.z, va.w, vb.x, vb.y, vb.z, vb.w};
            short8v hv, lv;
#pragma unroll
            for (int j = 0; j < 8; j++) {
                float f = RELU ? fmaxf(v[j], 0.f) : v[j];
                unsigned short h, l;
                bfsplit(f, h, l);
                hv[j] = (short)h; lv[j] = (short)l;
            }
            *(short8v*)&Ah[r][k8] = hv;
            *(short8v*)&Al[r][k8] = lv;
        }
        {
            int k2 = (tid & 15) << 1;
            int n4 = (tid >> 4) << 2;
            const float* bp = &B[(size_t)(k0 + k2) * ldb + n4];
            float4 va = *(const float4*)bp;
            float4 vb = *(const float4*)(bp + ldb);
            float v0[4] = {va.x, va.y, va.z, va.w};
            float v1[4] = {vb.x, vb.y, vb.z, vb.w};
#pragma unroll
            for (int j = 0; j < 4; j++) {
                unsigned short h0, l0, h1, l1;
                bfsplit(v0[j], h0, l0);
                bfsplit(v1[j], h1, l1);
                *(unsigned*)&Bh[n4 + j][k2] = (unsigned)h0 | ((unsigned)h1 << 16);
                *(unsigned*)&Bl[n4 + j][k2] = (unsigned)l0 | ((unsigned)l1 << 16);
            }
        }
        __syncthreads();
        short8v ah = *(short8v*)&Ah[(wid << 4) + lr][kg << 3];
        short8v al = *(short8v*)&Al[(wid << 4) + lr][kg << 3];
#pragma unroll
        for (int t = 0; t < 4; t++) {
            short8v bh = *(short8v*)&Bh[(t << 4) + lr][kg << 3];
            short8v bl = *(short8v*)&Bl[(t << 4) + lr][kg << 3];
            acc[t] = __builtin_amdgcn_mfma_f32_16x16x32_bf16(ah, bh, acc[t], 0, 0, 0);
            acc[t] = __builtin_amdgcn_mfma_f32_16x16x32_bf16(ah, bl, acc[t], 0, 0, 0);
            acc[t] = __builtin_amdgcn_mfma_f32_16x16x32_bf16(al, bh, acc[t], 0, 0, 0);
        }
        __syncthreads();
    }
}

// z/r gates FULL-K single block per tile + inline epilogue (no pbuf, no ep kernel).
// grid (NN/64, 8): y = gate g (y>>2) x col-tile (y&3). K01 = 0 (enc) or LT (dec).
__global__ __launch_bounds__(256) void k_zr1(
    const float* __restrict__ A0, int K01, const float* __restrict__ A1,
    const float* __restrict__ H, const float* __restrict__ A3,
    int la1, int la2, int la3,
    const float* __restrict__ Wx, const float* __restrict__ Wh,
    const float* __restrict__ bx, const float* __restrict__ bh,
    const float* __restrict__ x2, const float* __restrict__ ax2,
    const float* __restrict__ Wxr,
    float* __restrict__ gz, float* __restrict__ hr,
    unsigned short* __restrict__ hrb)
{
    __shared__ __align__(16) unsigned short Ah[64][40], Al[64][40],
                                            Bh[64][40], Bl[64][40];
    int tid = threadIdx.x;
    int wid = tid >> 6, lane = tid & 63, lr = lane & 15, kg = lane >> 4;
    int m0 = blockIdx.x << 6;
    int g = blockIdx.y >> 2;
    int n0 = (blockIdx.y & 3) << 6;
    float4v acc[4];
#pragma unroll
    for (int t = 0; t < 4; t++) acc[t] = (float4v){0.f, 0.f, 0.f, 0.f};
    const float* As[4] = {A0, A1, H, A3};
    const int ldas[4] = {K01, la1, la2, la3};
    const float* Bs[4] = {
        Wx + (size_t)(g * 2 + 0) * K01 * HE + n0,
        Wx + (size_t)(g * 2 + 1) * K01 * HE + n0,
        Wh + (size_t)(g * 2 + 0) * HE * HE + n0,
        Wh + (size_t)(g * 2 + 1) * HE * HE + n0};
    const int Ks[4] = {K01, K01, HE, HE};
#pragma unroll
    for (int s = 0; s < 4; s++) {
        if (Ks[s] > 0)
            mfma_seg<false>(Ah, Al, Bh, Bl, As[s], ldas[s], Bs[s], HE, Ks[s],
                            m0, tid, wid, lr, kg, acc);
    }
    // inline epilogue from registers
#pragma unroll
    for (int j = 0; j < 4; j++) {
        int row = m0 + (wid << 4) + (kg << 2) + j;
        float x0 = 0.f, x1 = 0.f, q0 = 0.f, q1 = 0.f;
        if (Wxr) {
            x0 = x2[2 * row]; x1 = x2[2 * row + 1];
            q0 = ax2[2 * row]; q1 = ax2[2 * row + 1];
        }
#pragma unroll
        for (int t = 0; t < 4; t++) {
            int col = n0 + (t << 4) + lr;   // 0..255 within gate
            float a = acc[t][j];
            if (Wxr) {
                const float* W0 = Wxr + (size_t)(g * 2 + 0) * FIN * HE;
                const float* W1 = Wxr + (size_t)(g * 2 + 1) * FIN * HE;
                a += x0 * W0[col] + x1 * W0[HE + col] + q0 * W1[col] + q1 * W1[HE + col];
            }
            a += bx[g * HE + col] + bh[g * HE + col];
            float s = 1.f / (1.f + expf(-a));
            size_t idx = (size_t)row * HE + col;
            if (g == 0) {
                gz[idx] = s;
            } else {
                float v = H[idx] * s;
                hr[idx] = v;
                hrb[idx] = f2bf(v);
            }
        }
    }
}

// candidate gate K-split (MFMA)
__global__ __launch_bounds__(256) void k_gt_ks(
    const float* __restrict__ A0, int K01, const float* __restrict__ A1,
    const float* __restrict__ hr, const float* __restrict__ A3,
    int la1, int la2, int la3,
    const float* __restrict__ Wx2, const float* __restrict__ Wh2,
    float* __restrict__ pbuf)
{
    __shared__ __align__(16) unsigned short Ah[64][40], Al[64][40],
                                            Bh[64][40], Bl[64][40];
    int tid = threadIdx.x;
    int wid = tid >> 6, lane = tid & 63, lr = lane & 15, kg = lane >> 4;
    int m0 = blockIdx.x << 6;
    int n0 = blockIdx.y << 6;
    float4v acc[4];
#pragma unroll
    for (int t = 0; t < 4; t++) acc[t] = (float4v){0.f, 0.f, 0.f, 0.f};
    const float* As[4] = {A0, A1, hr, A3};
    const int ldas[4] = {K01, la1, la2, la3};
    const float* Bs[4] = {
        Wx2 + n0,
        Wx2 + (size_t)K01 * HE + n0,
        Wh2 + n0,
        Wh2 + (size_t)HE * HE + n0};
    const int Ks[4] = {K01, K01, HE, HE};
    int chunk = (2 * K01 + 2 * HE) / GT_NZ;
    int lo = blockIdx.z * chunk, hi = lo + chunk;
    int off = 0;
#pragma unroll
    for (int s = 0; s < 4; s++) {
        int a = lo - off; a = a < 0 ? 0 : a;
        int b = hi - off; b = b > Ks[s] ? Ks[s] : b;
        if (b > a)
            mfma_seg<false>(Ah, Al, Bh, Bl, As[s] + a, ldas[s],
                            Bs[s] + (size_t)a * HE, HE, b - a,
                            m0, tid, wid, lr, kg, acc);
        off += Ks[s];
    }
    float* p = pbuf + (size_t)blockIdx.z * NN * HE;
#pragma unroll
    for (int t = 0; t < 4; t++)
#pragma unroll
        for (int j = 0; j < 4; j++)
            p[(size_t)(m0 + (wid << 4) + (kg << 2) + j) * HE + n0 + (t << 4) + lr] =
                acc[t][j];
}

// epilogue: H = z*H + (1-z)*tanh(...); bf16 mirror at (Hb, ldhb);
// if dlinW != nullptr also computes yhat = relu(H_new) @ dlinW + dlinb
__global__ void k_gt_ep(const float* __restrict__ pbuf,
                        const float* __restrict__ bx2, const float* __restrict__ bh2,
                        const float* __restrict__ gz,
                        const float* __restrict__ x2, const float* __restrict__ ax2,
                        const float* __restrict__ Wx2,
                        float* __restrict__ H,
                        unsigned short* __restrict__ Hb, int ldhb,
                        const float* __restrict__ dlinW, const float* __restrict__ dlinb,
                        float* __restrict__ yhat)
{
    int i = blockIdx.x * 256 + threadIdx.x;  // < NN*256/4
    const float4* p = (const float4*)pbuf;
    const size_t S = (size_t)NN * HE / 4;
    float4 a = p[i];
#pragma unroll
    for (int z = 1; z < GT_NZ; z++) {
        float4 v = p[(size_t)z * S + i];
        a.x += v.x; a.y += v.y; a.z += v.z; a.w += v.w;
    }
    int row = i >> 6, c = (i & 63) << 2;
    if (Wx2) {
        float x0 = x2[2 * row], x1 = x2[2 * row + 1];
        float q0 = ax2[2 * row], q1 = ax2[2 * row + 1];
        float4 w00 = *(const float4*)&Wx2[c];
        float4 w01 = *(const float4*)&Wx2[HE + c];
        float4 w10 = *(const float4*)&Wx2[2 * HE + c];
        float4 w11 = *(const float4*)&Wx2[3 * HE + c];
        a.x += x0 * w00.x + x1 * w01.x + q0 * w10.x + q1 * w11.x;
        a.y += x0 * w00.y + x1 * w01.y + q0 * w10.y + q1 * w11.y;
        a.z += x0 * w00.z + x1 * w01.z + q0 * w10.z + q1 * w11.z;
        a.w += x0 * w00.w + x1 * w01.w + q0 * w10.w + q1 * w11.w;
    }
    float4 b0 = *(const float4*)&bx2[c];
    float4 b1 = *(const float4*)&bh2[c];
    size_t idx = (size_t)row * HE + c;
    float4 z = *(const float4*)&gz[idx];
    float4 h = *(const float4*)&H[idx];
    float4 o;
    o.x = z.x * h.x + (1.f - z.x) * tanhf(a.x + b0.x + b1.x);
    o.y = z.y * h.y + (1.f - z.y) * tanhf(a.y + b0.y + b1.y);
    o.z = z.z * h.z + (1.f - z.z) * tanhf(a.z + b0.z + b1.z);
    o.w = z.w * h.w + (1.f - z.w) * tanhf(a.w + b0.w + b1.w);
    *(float4*)&H[idx] = o;
    short4v sb;
    sb[0] = (short)f2bf(o.x); sb[1] = (short)f2bf(o.y);
    sb[2] = (short)f2bf(o.z); sb[3] = (short)f2bf(o.w);
    *(short4v*)&Hb[(size_t)row * ldhb + c] = sb;
    if (dlinW) {
        float a0 = 0.f, a1 = 0.f;
        float ov[4] = {o.x, o.y, o.z, o.w};
#pragma unroll
        for (int j = 0; j < 4; j++) {
            float v = fmaxf(ov[j], 0.f);
            float2 b = *(const float2*)&dlinW[(c + j) * 2];
            a0 = fmaf(v, b.x, a0);
            a1 = fmaf(v, b.y, a1);
        }
        for (int off = 32; off > 0; off >>= 1) {
            a0 += __shfl_down(a0, off, 64);
            a1 += __shfl_down(a1, off, 64);
        }
        if ((threadIdx.x & 63) == 0) {
            yhat[2 * row] = a0 + dlinb[0];
            yhat[2 * row + 1] = a1 + dlinb[1];
        }
    }
}

// latent linear K-split (MFMA, relu on A)
__global__ __launch_bounds__(256) void k_lin_ks(
    const float* __restrict__ A, const float* __restrict__ B,
    float* __restrict__ pbuf)
{
    __shared__ __align__(16) unsigned short Ah[64][40], Al[64][40],
                                            Bh[64][40], Bl[64][40];
    int tid = threadIdx.x;
    int wid = tid >> 6, lane = tid & 63, lr = lane & 15, kg = lane >> 4;
    int m0 = blockIdx.x << 6;
    int n0 = blockIdx.y << 6;
    int lo = blockIdx.z << 5;  // 32 per slice
    float4v acc[4];
#pragma unroll
    for (int t = 0; t < 4; t++) acc[t] = (float4v){0.f, 0.f, 0.f, 0.f};
    mfma_seg<true>(Ah, Al, Bh, Bl, A + lo, HE, B + (size_t)lo * LT + n0, LT, 32,
                   m0, tid, wid, lr, kg, acc);
    float* p = pbuf + (size_t)blockIdx.z * NN * LT;
#pragma unroll
    for (int t = 0; t < 4; t++)
#pragma unroll
        for (int j = 0; j < 4; j++)
            p[(size_t)(m0 + (wid << 4) + (kg << 2) + j) * LT + n0 + (t << 4) + lr] =
                acc[t][j];
}

// writes zlat fp32 + bf16 mirror into xcat_b[:, 0:128]
__global__ void k_lin_ep(const float* __restrict__ pbuf,
                         const float* __restrict__ bias, float* __restrict__ out,
                         unsigned short* __restrict__ zb)
{
    int i = blockIdx.x * 256 + threadIdx.x;  // < NN*128/4
    const float4* p = (const float4*)pbuf;
    const size_t S = (size_t)NN * LT / 4;
    int row = i >> 5, c = (i & 31) << 2;
    float4 bb = *(const float4*)&bias[c];
    float4 s = make_float4(bb.x, bb.y, bb.z, bb.w);
#pragma unroll
    for (int z = 0; z < LIN_NZ; z++) {
        float4 v = p[z * S + i];
        s.x += v.x; s.y += v.y; s.z += v.z; s.w += v.w;
    }
    ((float4*)out)[i] = s;
    short4v sb;
    sb[0] = (short)f2bf(s.x); sb[1] = (short)f2bf(s.y);
    sb[2] = (short)f2bf(s.z); sb[3] = (short)f2bf(s.w);
    *(short4v*)&zb[(size_t)row * XC + c] = sb;
}

// fp32 -> bf16 mirror with output stride (for initial states)
__global__ void k_cvtb(const float* __restrict__ in, unsigned short* __restrict__ outb,
                       int ldo) {
    int i = blockIdx.x * 256 + threadIdx.x;
    int r = i >> 8, c = i & 255;
    outb[(size_t)r * ldo + c] = f2bf(in[i]);
}

extern "C" void kernel_launch(void* const* d_in, const int* in_sizes, int n_in,
                              void* d_out, int out_size, void* d_ws, size_t ws_size,
                              hipStream_t stream) {
    (void)in_sizes; (void)n_in; (void)out_size; (void)ws_size;
    const float* x_seq = (const float*)d_in[0];
    const int* ei = (const int*)d_in[1];
    const float* ews = (const float*)d_in[2];
    const float* h_enc_in = (const float*)d_in[3];
    const float* h_dec_in = (const float*)d_in[4];
    const float* encWx = (const float*)d_in[5];
    const float* encbx = (const float*)d_in[6];
    const float* encWh = (const float*)d_in[7];
    const float* encbh = (const float*)d_in[8];
    const float* elinW = (const float*)d_in[9];
    const float* elinb = (const float*)d_in[10];
    const float* decWx = (const float*)d_in[11];
    const float* decbx = (const float*)d_in[12];
    const float* decWh = (const float*)d_in[13];
    const float* decbh = (const float*)d_in[14];
    const float* dlinW = (const float*)d_in[15];
    const float* dlinb = (const float*)d_in[16];
    float* out = (float*)d_out;

    float* W = (float*)d_ws;
    float* h_enc = W; W += (size_t)NN * HE;
    float* h_dec = W; W += (size_t)NN * HE;
    float* aggh  = W; W += (size_t)NN * HE;
    float* hr    = W; W += (size_t)NN * HE;
    float* agghr = W; W += (size_t)NN * HE;
    float* gz    = W; W += (size_t)NN * HE;
    float* zlat  = W; W += (size_t)NN * LT;
    float* Y     = W; W += (size_t)NN * XC;
    float* yhat  = W; W += (size_t)NN * FIN;
    float* aggx2 = W; W += (size_t)NN * FIN;
    float* dinv_d = W; W += NN;
    unsigned short* Mb = (unsigned short*)W; W += (size_t)NN * NN / 2;
    float* pbuf  = W; W += (size_t)8 * NN * XC;  // generous: max user 12.6 MB
    unsigned short* Hen_b = (unsigned short*)W; W += (size_t)NN * HE / 2;
    unsigned short* hr_b  = (unsigned short*)W; W += (size_t)NN * HE / 2;
    unsigned short* xcat_b = (unsigned short*)W; W += (size_t)NN * XC / 2;
    float* deg_all = W; W += (size_t)T_OBS * NN;
    int*   cnt_all = (int*)W; W += (size_t)T_OBS * NN;
    float* dinv_all = W; W += (size_t)T_OBS * NN;
    float* csr_nrm_all = W; W += (size_t)T_OBS * EE;
    float* aggx_all = W; W += (size_t)T_OBS * NN * FIN;
    int* roff_all = (int*)W; W += (size_t)T_OBS * (NN + 1) + 1;
    int* cur_all = (int*)W; W += (size_t)T_OBS * NN;
    int* csr_src_all = (int*)W; W += (size_t)T_OBS * EE;

    // ---- batched sparse prep ----
    hipMemsetAsync(deg_all, 0, sizeof(float) * T_OBS * NN * 2, stream);  // deg+cnt
    k_degcnt_lds<<<dim3(8, T_OBS), 256, 0, stream>>>(ei, ews, deg_all, cnt_all);
    k_scan_b<<<T_OBS, 256, 0, stream>>>(cnt_all, deg_all, roff_all, cur_all, dinv_all);
    k_scatter2_b<<<dim3(EE / 256, T_OBS), 256, 0, stream>>>(ei, ews, dinv_all, cur_all,
                                                            csr_src_all, csr_nrm_all);
    k_spmm2_b<<<dim3(NN / 256, T_OBS), 256, 0, stream>>>(roff_all, csr_src_all,
                                                         csr_nrm_all, x_seq, aggx_all);

    hipMemcpyAsync(h_enc, h_enc_in, sizeof(float) * NN * HE, hipMemcpyDeviceToDevice, stream);
    hipMemcpyAsync(h_dec, h_dec_in, sizeof(float) * NN * HE, hipMemcpyDeviceToDevice, stream);
    k_cvtb<<<NN * HE / 256, 256, 0, stream>>>(h_enc_in, Hen_b, HE);
    k_cvtb<<<NN * HE / 256, 256, 0, stream>>>(h_dec_in, xcat_b + LT, XC);

    for (int step = 0; step < T_OBS + PREDN - 1; ++step) {
        bool sparse = step < T_OBS;
        const float* xin;
        const float* aggx_s;
        const int* roff = roff_all + step * (NN + 1);
        const int* csr_src = csr_src_all + (size_t)step * EE;
        const float* csr_nrm = csr_nrm_all + (size_t)step * EE;
        if (sparse) {
            xin = x_seq + (size_t)step * NN * FIN;
            aggx_s = aggx_all + (size_t)step * NN * FIN;
        } else {
            k_ddeg<<<NN, 256, 0, stream>>>(yhat, dinv_d);
            k_dM2<<<NN, 256, 0, stream>>>(yhat, dinv_d, Mb, aggx2);
            xin = yhat;
            aggx_s = aggx2;
        }

        // ======= encoder GRU (x: F=2 via rank-2 epilogue, H: h_enc) =======
        if (sparse) {
            k_spmm_vb<HE, 64><<<NN / 4, 256, 0, stream>>>(roff, csr_src, csr_nrm,
                                                          Hen_b, aggh, HE);
        } else {
            k_dmm_mfb<HE><<<dim3(NN / 64, HE / 64, DMM_NZ), 256, 0, stream>>>(Mb, Hen_b, pbuf);
            k_redks<HE, DMM_NZ><<<NN * HE / 4 / 256, 256, 0, stream>>>(pbuf, aggh);
        }
        k_zr1<<<dim3(NN / 64, 8), 256, 0, stream>>>(xin, 0, aggx_s, h_enc, aggh,
                                                    FIN, HE, HE, encWx, encWh,
                                                    encbx, encbh, xin, aggx_s, encWx,
                                                    gz, hr, hr_b);
        if (sparse) {
            k_spmm_vb<HE, 64><<<NN / 4, 256, 0, stream>>>(roff, csr_src, csr_nrm,
                                                          hr_b, agghr, HE);
        } else {
            k_dmm_mfb<HE><<<dim3(NN / 64, HE / 64, DMM_NZ), 256, 0, stream>>>(Mb, hr_b, pbuf);
            k_redks<HE, DMM_NZ><<<NN * HE / 4 / 256, 256, 0, stream>>>(pbuf, agghr);
        }
        k_gt_ks<<<dim3(NN / 64, 4, GT_NZ), 256, 0, stream>>>(xin, 0, aggx_s, hr, agghr,
                                                             FIN, HE, HE,
                                                             encWx + 4 * FIN * HE,
                                                             encWh + 4 * HE * HE, pbuf);
        k_gt_ep<<<NN * HE / 4 / 256, 256, 0, stream>>>(pbuf, encbx + 2 * HE,
                                                       encbh + 2 * HE, gz,
                                                       xin, aggx_s, encWx + 4 * FIN * HE,
                                                       h_enc, Hen_b, HE,
                                                       nullptr, nullptr, nullptr);
        k_lin_ks<<<dim3(NN / 64, 2, LIN_NZ), 256, 0, stream>>>(h_enc, elinW, pbuf);
        k_lin_ep<<<NN * LT / 4 / 256, 256, 0, stream>>>(pbuf, elinb, zlat, xcat_b);

        // ======= decoder GRU: combined agg of [zlat | h_dec] = xcat_b =======
        if (sparse) {
            k_spmm_vb<XC, 128><<<NN / 2, 256, 0, stream>>>(roff, csr_src, csr_nrm,
                                                           xcat_b, Y, XC);
        } else {
            k_dmm_mfb<XC><<<dim3(NN / 64, XC / 64, DMM_NZ), 256, 0, stream>>>(Mb, xcat_b, pbuf);
            k_redks<XC, DMM_NZ><<<NN * XC / 4 / 256, 256, 0, stream>>>(pbuf, Y);
        }
        k_zr1<<<dim3(NN / 64, 8), 256, 0, stream>>>(zlat, LT, Y, h_dec, Y + LT,
                                                    XC, HE, XC, decWx, decWh,
                                                    decbx, decbh,
                                                    nullptr, nullptr, nullptr,
                                                    gz, hr, hr_b);
        if (sparse) {
            k_spmm_vb<HE, 64><<<NN / 4, 256, 0, stream>>>(roff, csr_src, csr_nrm,
                                                          hr_b, agghr, HE);
        } else {
            k_dmm_mfb<HE><<<dim3(NN / 64, HE / 64, DMM_NZ), 256, 0, stream>>>(Mb, hr_b, pbuf);
            k_redks<HE, DMM_NZ><<<NN * HE / 4 / 256, 256, 0, stream>>>(pbuf, agghr);
        }
        k_gt_ks<<<dim3(NN / 64, 4, GT_NZ), 256, 0, stream>>>(zlat, LT, Y, hr, agghr,
                                                             XC, HE, HE,
                                                             decWx + 4 * LT * HE,
                                                             decWh + 4 * HE * HE, pbuf);
        k_gt_ep<<<NN * HE / 4 / 256, 256, 0, stream>>>(pbuf, decbx + 2 * HE,
                                                       decbh + 2 * HE, gz,
                                                       nullptr, nullptr, nullptr,
                                                       h_dec, xcat_b + LT, XC,
                                                       dlinW, dlinb, yhat);

        if (step >= T_OBS - 1) {
            hipMemcpyAsync(out + (size_t)(step - (T_OBS - 1)) * NN * FIN, yhat,
                           sizeof(float) * NN * FIN, hipMemcpyDeviceToDevice, stream);
        }
    }
}

// Round 15
// 1618.382 us; speedup vs baseline: 1.1044x; 1.1044x over previous
//
#include <hip/hip_runtime.h>
#include <math.h>

#define NN 2048
#define EE 65536
#define T_OBS 6
#define FIN 2
#define HE 256
#define LT 128
#define XC 384          // xcat width: [zlat(128) | h_dec(256)]
#define PREDN 6
#define DMM_NZ 8
#define ZR_NZ 4
#define GT_NZ 8
#define LIN_NZ 8

typedef __attribute__((ext_vector_type(8))) short short8v;
typedef __attribute__((ext_vector_type(4))) short short4v;
typedef __attribute__((ext_vector_type(4))) float float4v;

static __device__ __forceinline__ unsigned short f2bf(float f) {
    union { float f; unsigned u; } v; v.f = f;
    unsigned r = v.u + 0x7fff + ((v.u >> 16) & 1);
    return (unsigned short)(r >> 16);
}

static __device__ __forceinline__ void bfsplit(float f, unsigned short& h,
                                               unsigned short& l) {
    unsigned u = __float_as_uint(f);
    h = (unsigned short)(u >> 16);
    float hf = __uint_as_float(u & 0xffff0000u);
    l = (unsigned short)(__float_as_uint(f - hf) >> 16);
}

static __device__ __forceinline__ float bf2f(unsigned short b) {
    return __uint_as_float(((unsigned)b) << 16);
}

// ---------------- batched sparse graph prep ----------------
__global__ void k_degcnt_lds(const int* __restrict__ ei, const float* __restrict__ ews,
                             float* __restrict__ deg_all, int* __restrict__ cnt_all) {
    __shared__ float ldeg[NN];
    __shared__ int lcnt[NN];
    int tg = blockIdx.y;
    const int* src = ei + (size_t)tg * 2 * EE;
    const int* dst = src + EE;
    const float* ew = ews + (size_t)tg * EE;
    for (int i = threadIdx.x; i < NN; i += 256) { ldeg[i] = 0.f; lcnt[i] = 0; }
    __syncthreads();
    const int EPB = EE / 8;
    int e0 = blockIdx.x * EPB;
    for (int e = e0 + threadIdx.x; e < e0 + EPB; e += 256) {
        atomicAdd(&ldeg[src[e]], ew[e]);
        atomicAdd(&lcnt[dst[e]], 1);
    }
    __syncthreads();
    for (int i = threadIdx.x; i < NN; i += 256) {
        float d = ldeg[i]; int cc = lcnt[i];
        if (d != 0.f) atomicAdd(&deg_all[tg * NN + i], d);
        if (cc) atomicAdd(&cnt_all[tg * NN + i], cc);
    }
}

__global__ void k_scan_b(const int* __restrict__ cnt_all, const float* __restrict__ deg_all,
                         int* __restrict__ roff_all, int* __restrict__ cur_all,
                         float* __restrict__ dinv_all) {
    __shared__ int part[256];
    int tg = blockIdx.x;
    const int* cnt = cnt_all + tg * NN;
    const float* deg = deg_all + tg * NN;
    int* roff = roff_all + tg * (NN + 1);
    int* cur = cur_all + tg * NN;
    float* dinv = dinv_all + tg * NN;
    int t = threadIdx.x;
#pragma unroll
    for (int i = t; i < NN; i += 256) {
        float d = deg[i];
        dinv[i] = d > 0.f ? 1.f / sqrtf(d) : 0.f;
    }
    int loc[8];
    int s = 0;
#pragma unroll
    for (int i = 0; i < 8; i++) { loc[i] = cnt[t * 8 + i]; s += loc[i]; }
    part[t] = s;
    __syncthreads();
    for (int off = 1; off < 256; off <<= 1) {
        int v = (t >= off) ? part[t - off] : 0;
        __syncthreads();
        part[t] += v;
        __syncthreads();
    }
    int run = (t == 0) ? 0 : part[t - 1];
#pragma unroll
    for (int i = 0; i < 8; i++) {
        int idx = t * 8 + i;
        roff[idx] = run;
        cur[idx] = run;
        run += loc[i];
    }
    if (t == 255) roff[NN] = run;
}

__global__ void k_scatter2_b(const int* __restrict__ ei, const float* __restrict__ ews,
                             const float* __restrict__ dinv_all, int* __restrict__ cur_all,
                             int* __restrict__ csr_src_all, float* __restrict__ csr_nrm_all) {
    int tg = blockIdx.y;
    int e = blockIdx.x * blockDim.x + threadIdx.x;
    const int* src = ei + (size_t)tg * 2 * EE;
    const int* dst = src + EE;
    const float* ew = ews + (size_t)tg * EE;
    const float* dinv = dinv_all + tg * NN;
    if (e < EE) {
        int s = src[e], d = dst[e];
        int p = atomicAdd(&cur_all[tg * NN + d], 1);
        csr_src_all[(size_t)tg * EE + p] = s;
        csr_nrm_all[(size_t)tg * EE + p] = -dinv[s] * ew[e] * dinv[d];
    }
}

__global__ void k_spmm2_b(const int* __restrict__ roff_all, const int* __restrict__ csr_src_all,
                          const float* __restrict__ csr_nrm_all, const float* __restrict__ x_seq,
                          float* __restrict__ aggx_all) {
    int tg = blockIdx.y;
    int nid = blockIdx.x * blockDim.x + threadIdx.x;
    if (nid < NN) {
        const int* roff = roff_all + tg * (NN + 1);
        const int* csr_src = csr_src_all + (size_t)tg * EE;
        const float* csr_nrm = csr_nrm_all + (size_t)tg * EE;
        const float* X = x_seq + (size_t)tg * NN * FIN;
        int s0 = roff[nid], s1 = roff[nid + 1];
        float a0 = 0.f, a1 = 0.f;
        for (int s = s0; s < s1; ++s) {
            int i = csr_src[s]; float w = csr_nrm[s];
            float2 xv = *(const float2*)&X[2 * i];
            a0 = fmaf(w, xv.x, a0);
            a1 = fmaf(w, xv.y, a1);
        }
        aggx_all[(size_t)tg * NN * FIN + 2 * nid] = a0;
        aggx_all[(size_t)tg * NN * FIN + 2 * nid + 1] = a1;
    }
}

// CSR SpMM gathering bf16 X; TPN threads per node; out stride ldo
template <int F, int TPN>
__global__ void k_spmm_vb(const int* __restrict__ roff, const int* __restrict__ csr_src,
                          const float* __restrict__ csr_nrm,
                          const unsigned short* __restrict__ Xb,
                          float* __restrict__ out, int ldo) {
    const int NPB = 256 / TPN;
    int w = threadIdx.x / TPN, l = threadIdx.x % TPN;
    int nid = blockIdx.x * NPB + w;
    int c = l << 2;
    int s0 = roff[nid], s1 = roff[nid + 1];
    float4 acc = make_float4(0.f, 0.f, 0.f, 0.f);
    int s = s0;
    for (; s + 8 <= s1; s += 8) {
        int is[8]; float ws[8];
#pragma unroll
        for (int j = 0; j < 8; j++) { is[j] = csr_src[s + j]; ws[j] = csr_nrm[s + j]; }
        if (c < F) {
            short4v xv[8];
#pragma unroll
            for (int j = 0; j < 8; j++)
                xv[j] = *(const short4v*)&Xb[(size_t)is[j] * F + c];
#pragma unroll
            for (int j = 0; j < 8; j++) {
                acc.x = fmaf(ws[j], bf2f((unsigned short)xv[j][0]), acc.x);
                acc.y = fmaf(ws[j], bf2f((unsigned short)xv[j][1]), acc.y);
                acc.z = fmaf(ws[j], bf2f((unsigned short)xv[j][2]), acc.z);
                acc.w = fmaf(ws[j], bf2f((unsigned short)xv[j][3]), acc.w);
            }
        }
    }
    for (; s < s1; ++s) {
        int i0 = csr_src[s]; float w0 = csr_nrm[s];
        if (c < F) {
            short4v xv = *(const short4v*)&Xb[(size_t)i0 * F + c];
            acc.x = fmaf(w0, bf2f((unsigned short)xv[0]), acc.x);
            acc.y = fmaf(w0, bf2f((unsigned short)xv[1]), acc.y);
            acc.z = fmaf(w0, bf2f((unsigned short)xv[2]), acc.z);
            acc.w = fmaf(w0, bf2f((unsigned short)xv[3]), acc.w);
        }
    }
    if (c < F) *(float4*)&out[(size_t)nid * ldo + c] = acc;
}

// ---------------- dense graph prep (rollout) ----------------
__global__ void k_ddeg(const float* __restrict__ c, float* __restrict__ dinv) {
    int i = blockIdx.x;
    int t = threadIdx.x;
    float xi = c[2 * i], yi = c[2 * i + 1];
    float s = 0.f;
    for (int j = t; j < NN; j += 256) {
        float dx = xi - c[2 * j], dy = yi - c[2 * j + 1];
        float d = sqrtf(dx * dx + dy * dy);
        if (d > 0.f && d < 0.5f) s += 2.f * d;
    }
    __shared__ float red[256];
    red[t] = s;
    __syncthreads();
    for (int off = 128; off > 0; off >>= 1) {
        if (t < off) red[t] += red[t + off];
        __syncthreads();
    }
    if (t == 0) {
        float d = red[0];
        dinv[i] = d > 0.f ? 1.f / sqrtf(d) : 0.f;
    }
}

// fused: bf16 M row + encoder F=2 aggregation (M @ yhat)
__global__ void k_dM2(const float* __restrict__ c, const float* __restrict__ dinv,
                      unsigned short* __restrict__ Mb, float* __restrict__ ax) {
    int i = blockIdx.x;
    int t = threadIdx.x;
    float xi = c[2 * i], yi = c[2 * i + 1], di = dinv[i];
    float a0 = 0.f, a1 = 0.f;
    for (int j = t; j < NN; j += 256) {
        float dx = xi - c[2 * j], dy = yi - c[2 * j + 1];
        float d = sqrtf(dx * dx + dy * dy);
        float w = (d > 0.f && d < 0.5f) ? 2.f * d : 0.f;
        float v = -(di * w) * dinv[j];
        Mb[(size_t)i * NN + j] = f2bf(v);
        a0 = fmaf(v, c[2 * j], a0);
        a1 = fmaf(v, c[2 * j + 1], a1);
    }
    __shared__ float r0[256], r1[256];
    r0[t] = a0;
    r1[t] = a1;
    __syncthreads();
    for (int off = 128; off > 0; off >>= 1) {
        if (t < off) { r0[t] += r0[t + off]; r1[t] += r1[t + off]; }
        __syncthreads();
    }
    if (t == 0) { ax[2 * i] = r0[0]; ax[2 * i + 1] = r1[0]; }
}

// dense agg via bf16 MFMA, X already bf16 (row-major [NN][F])
template <int F>
__global__ __launch_bounds__(256) void k_dmm_mfb(
    const unsigned short* __restrict__ Mb, const unsigned short* __restrict__ Xb,
    float* __restrict__ pbuf)
{
    __shared__ __align__(16) unsigned short Ms[64][72];
    __shared__ __align__(16) unsigned short Xs[64][72];
    const int tid = threadIdx.x;
    const int wid = tid >> 6, lane = tid & 63;
    const int m0 = blockIdx.x << 6, n0 = blockIdx.y << 6;
    const int kb0 = blockIdx.z << 8;
    const int lr = lane & 15;
    const int kg = lane >> 4;
    float4v acc[4];
#pragma unroll
    for (int t = 0; t < 4; t++) acc[t] = (float4v){0.f, 0.f, 0.f, 0.f};

    for (int kb = kb0; kb < kb0 + 256; kb += 64) {
#pragma unroll
        for (int it = 0; it < 2; it++) {
            int i = tid + it * 256;
            int r = i >> 3, c8 = (i & 7) << 3;
            *(short8v*)&Ms[r][c8] =
                *(const short8v*)&Mb[(size_t)(m0 + r) * NN + kb + c8];
        }
#pragma unroll
        for (int it = 0; it < 2; it++) {
            int i = tid + it * 256;
            int k2 = (i & 31) << 1;
            int n4 = (i >> 5) << 2;
            short4v va = *(const short4v*)&Xb[(size_t)(kb + k2) * F + n0 + n4];
            short4v vb = *(const short4v*)&Xb[(size_t)(kb + k2 + 1) * F + n0 + n4];
#pragma unroll
            for (int j = 0; j < 4; j++)
                *(unsigned*)&Xs[n4 + j][k2] =
                    (unsigned)(unsigned short)va[j] |
                    ((unsigned)(unsigned short)vb[j] << 16);
        }
        __syncthreads();
#pragma unroll
        for (int kh = 0; kh < 2; kh++) {
            int kk = kh * 32 + kg * 8;
            short8v a = *(const short8v*)&Ms[(wid << 4) + lr][kk];
#pragma unroll
            for (int t = 0; t < 4; t++) {
                short8v b = *(const short8v*)&Xs[(t << 4) + lr][kk];
                acc[t] = __builtin_amdgcn_mfma_f32_16x16x32_bf16(a, b, acc[t], 0, 0, 0);
            }
        }
        __syncthreads();
    }
    float* p = pbuf + (size_t)blockIdx.z * NN * F;
#pragma unroll
    for (int t = 0; t < 4; t++)
#pragma unroll
        for (int j = 0; j < 4; j++)
            p[(size_t)(m0 + (wid << 4) + (kg << 2) + j) * F + n0 + (t << 4) + lr] =
                acc[t][j];
}

template <int F, int NZ>
__global__ void k_redks(const float* __restrict__ pbuf, float* __restrict__ out) {
    const int TOT = NN * F / 4;
    int i = blockIdx.x * blockDim.x + threadIdx.x;
    if (i < TOT) {
        const float4* p = (const float4*)pbuf;
        float4 s = p[i];
#pragma unroll
        for (int z = 1; z < NZ; z++) {
            float4 v = p[(size_t)z * TOT + i];
            s.x += v.x; s.y += v.y; s.z += v.z; s.w += v.w;
        }
        ((float4*)out)[i] = s;
    }
}

// ---------------- bf16x3 MFMA GEMM segment core (r8 proven) ----------------
template <bool RELU>
__device__ __forceinline__ void mfma_seg(
    unsigned short (*Ah)[40], unsigned short (*Al)[40],
    unsigned short (*Bh)[40], unsigned short (*Bl)[40],
    const float* __restrict__ A, int lda,
    const float* __restrict__ B, int ldb, int K,
    int m0, int tid, int wid, int lr, int kg, float4v (&acc)[4])
{
    for (int k0 = 0; k0 < K; k0 += 32) {
        {
            int r = tid >> 2, k8 = (tid & 3) << 3;
            const float* ap = &A[(size_t)(m0 + r) * lda + k0 + k8];
            float4 va = *(const float4*)ap;
            float4 vb = *(const float4*)(ap + 4);
            float v[8] = {va.x, va.y, va.z, va.w, vb.x, vb.y, vb.z, vb.w};
            short8v hv, lv;
#pragma unroll
            for (int j = 0; j < 8; j++) {
                float f = RELU ? fmaxf(v[j], 0.f) : v[j];
                unsigned short h, l;
                bfsplit(f, h, l);
                hv[j] = (short)h; lv[j] = (short)l;
            }
            *(short8v*)&Ah[r][k8] = hv;
            *(short8v*)&Al[r][k8] = lv;
        }
        {
            int k2 = (tid & 15) << 1;
            int n4 = (tid >> 4) << 2;
            const float* bp = &B[(size_t)(k0 + k2) * ldb + n4];
            float4 va = *(const float4*)bp;
            float4 vb = *(const float4*)(bp + ldb);
            float v0[4] = {va.x, va.y, va.z, va.w};
            float v1[4] = {vb.x, vb.y, vb.z, vb.w};
#pragma unroll
            for (int j = 0; j < 4; j++) {
                unsigned short h0, l0, h1, l1;
                bfsplit(v0[j], h0, l0);
                bfsplit(v1[j], h1, l1);
                *(unsigned*)&Bh[n4 + j][k2] = (unsigned)h0 | ((unsigned)h1 << 16);
                *(unsigned*)&Bl[n4 + j][k2] = (unsigned)l0 | ((unsigned)l1 << 16);
            }
        }
        __syncthreads();
        short8v ah = *(short8v*)&Ah[(wid << 4) + lr][kg << 3];
        short8v al = *(short8v*)&Al[(wid << 4) + lr][kg << 3];
#pragma unroll
        for (int t = 0; t < 4; t++) {
            short8v bh = *(short8v*)&Bh[(t << 4) + lr][kg << 3];
            short8v bl = *(short8v*)&Bl[(t << 4) + lr][kg << 3];
            acc[t] = __builtin_amdgcn_mfma_f32_16x16x32_bf16(ah, bh, acc[t], 0, 0, 0);
            acc[t] = __builtin_amdgcn_mfma_f32_16x16x32_bf16(ah, bl, acc[t], 0, 0, 0);
            acc[t] = __builtin_amdgcn_mfma_f32_16x16x32_bf16(al, bh, acc[t], 0, 0, 0);
        }
        __syncthreads();
    }
}

// z/r gates K-split (MFMA). K01 = 0 (enc) or LT (dec). Per-segment lda args.
__global__ __launch_bounds__(256) void k_zr_ks(
    const float* __restrict__ A0, int K01, const float* __restrict__ A1,
    const float* __restrict__ H, const float* __restrict__ A3,
    int la1, int la2, int la3,
    const float* __restrict__ Wx, const float* __restrict__ Wh,
    float* __restrict__ pbuf)
{
    __shared__ __align__(16) unsigned short Ah[64][40], Al[64][40],
                                            Bh[64][40], Bl[64][40];
    int tid = threadIdx.x;
    int wid = tid >> 6, lane = tid & 63, lr = lane & 15, kg = lane >> 4;
    int m0 = blockIdx.x << 6;
    int g = blockIdx.y >> 2;
    int n0 = (blockIdx.y & 3) << 6;
    float4v acc[4];
#pragma unroll
    for (int t = 0; t < 4; t++) acc[t] = (float4v){0.f, 0.f, 0.f, 0.f};
    const float* As[4] = {A0, A1, H, A3};
    const int ldas[4] = {K01, la1, la2, la3};
    const float* Bs[4] = {
        Wx + (size_t)(g * 2 + 0) * K01 * HE + n0,
        Wx + (size_t)(g * 2 + 1) * K01 * HE + n0,
        Wh + (size_t)(g * 2 + 0) * HE * HE + n0,
        Wh + (size_t)(g * 2 + 1) * HE * HE + n0};
    const int Ks[4] = {K01, K01, HE, HE};
    int chunk = (2 * K01 + 2 * HE) / ZR_NZ;
    int lo = blockIdx.z * chunk, hi = lo + chunk;
    int off = 0;
#pragma unroll
    for (int s = 0; s < 4; s++) {
        int a = lo - off; a = a < 0 ? 0 : a;
        int b = hi - off; b = b > Ks[s] ? Ks[s] : b;
        if (b > a)
            mfma_seg<false>(Ah, Al, Bh, Bl, As[s] + a, ldas[s],
                            Bs[s] + (size_t)a * HE, HE, b - a,
                            m0, tid, wid, lr, kg, acc);
        off += Ks[s];
    }
    float* p = pbuf + (size_t)blockIdx.z * NN * 512;
    int cbase = (g << 8) + n0;
#pragma unroll
    for (int t = 0; t < 4; t++)
#pragma unroll
        for (int j = 0; j < 4; j++)
            p[(size_t)(m0 + (wid << 4) + (kg << 2) + j) * 512 + cbase + (t << 4) + lr] =
                acc[t][j];
}

// epilogue: + rank-2 (x,aggx) terms when Wx != nullptr; writes hr + bf16 mirror
__global__ void k_zr_ep(const float* __restrict__ pbuf,
                        const float* __restrict__ bx, const float* __restrict__ bh,
                        const float* __restrict__ H,
                        const float* __restrict__ x2, const float* __restrict__ ax2,
                        const float* __restrict__ Wx,
                        float* __restrict__ gz, float* __restrict__ hr,
                        unsigned short* __restrict__ hrb)
{
    int i = blockIdx.x * 256 + threadIdx.x;  // < NN*512/4
    const float4* p = (const float4*)pbuf;
    const size_t S = (size_t)NN * 512 / 4;
    float4 a = p[i];
#pragma unroll
    for (int z = 1; z < ZR_NZ; z++) {
        float4 v = p[(size_t)z * S + i];
        a.x += v.x; a.y += v.y; a.z += v.z; a.w += v.w;
    }
    int row = i >> 7, c = (i & 127) << 2;
    int g = c >> 8, cc = c & 255;
    if (Wx) {
        float x0 = x2[2 * row], x1 = x2[2 * row + 1];
        float q0 = ax2[2 * row], q1 = ax2[2 * row + 1];
        const float* W0 = Wx + (size_t)(g * 2 + 0) * FIN * HE;
        const float* W1 = Wx + (size_t)(g * 2 + 1) * FIN * HE;
        float4 w00 = *(const float4*)&W0[cc];
        float4 w01 = *(const float4*)&W0[HE + cc];
        float4 w10 = *(const float4*)&W1[cc];
        float4 w11 = *(const float4*)&W1[HE + cc];
        a.x += x0 * w00.x + x1 * w01.x + q0 * w10.x + q1 * w11.x;
        a.y += x0 * w00.y + x1 * w01.y + q0 * w10.y + q1 * w11.y;
        a.z += x0 * w00.z + x1 * w01.z + q0 * w10.z + q1 * w11.z;
        a.w += x0 * w00.w + x1 * w01.w + q0 * w10.w + q1 * w11.w;
    }
    float4 b0 = *(const float4*)&bx[c];
    float4 b1 = *(const float4*)&bh[c];
    float4 s;
    s.x = 1.f / (1.f + expf(-(a.x + b0.x + b1.x)));
    s.y = 1.f / (1.f + expf(-(a.y + b0.y + b1.y)));
    s.z = 1.f / (1.f + expf(-(a.z + b0.z + b1.z)));
    s.w = 1.f / (1.f + expf(-(a.w + b0.w + b1.w)));
    if (c < HE) {
        *(float4*)&gz[(size_t)row * HE + c] = s;
    } else {
        size_t idx = (size_t)row * HE + cc;
        float4 h = *(const float4*)&H[idx];
        s.x *= h.x; s.y *= h.y; s.z *= h.z; s.w *= h.w;
        *(float4*)&hr[idx] = s;
        short4v sb;
        sb[0] = (short)f2bf(s.x); sb[1] = (short)f2bf(s.y);
        sb[2] = (short)f2bf(s.z); sb[3] = (short)f2bf(s.w);
        *(short4v*)&hrb[idx] = sb;
    }
}

// candidate gate K-split (MFMA)
__global__ __launch_bounds__(256) void k_gt_ks(
    const float* __restrict__ A0, int K01, const float* __restrict__ A1,
    const float* __restrict__ hr, const float* __restrict__ A3,
    int la1, int la2, int la3,
    const float* __restrict__ Wx2, const float* __restrict__ Wh2,
    float* __restrict__ pbuf)
{
    __shared__ __align__(16) unsigned short Ah[64][40], Al[64][40],
                                            Bh[64][40], Bl[64][40];
    int tid = threadIdx.x;
    int wid = tid >> 6, lane = tid & 63, lr = lane & 15, kg = lane >> 4;
    int m0 = blockIdx.x << 6;
    int n0 = blockIdx.y << 6;
    float4v acc[4];
#pragma unroll
    for (int t = 0; t < 4; t++) acc[t] = (float4v){0.f, 0.f, 0.f, 0.f};
    const float* As[4] = {A0, A1, hr, A3};
    const int ldas[4] = {K01, la1, la2, la3};
    const float* Bs[4] = {
        Wx2 + n0,
        Wx2 + (size_t)K01 * HE + n0,
        Wh2 + n0,
        Wh2 + (size_t)HE * HE + n0};
    const int Ks[4] = {K01, K01, HE, HE};
    int chunk = (2 * K01 + 2 * HE) / GT_NZ;
    int lo = blockIdx.z * chunk, hi = lo + chunk;
    int off = 0;
#pragma unroll
    for (int s = 0; s < 4; s++) {
        int a = lo - off; a = a < 0 ? 0 : a;
        int b = hi - off; b = b > Ks[s] ? Ks[s] : b;
        if (b > a)
            mfma_seg<false>(Ah, Al, Bh, Bl, As[s] + a, ldas[s],
                            Bs[s] + (size_t)a * HE, HE, b - a,
                            m0, tid, wid, lr, kg, acc);
        off += Ks[s];
    }
    float* p = pbuf + (size_t)blockIdx.z * NN * HE;
#pragma unroll
    for (int t = 0; t < 4; t++)
#pragma unroll
        for (int j = 0; j < 4; j++)
            p[(size_t)(m0 + (wid << 4) + (kg << 2) + j) * HE + n0 + (t << 4) + lr] =
                acc[t][j];
}

// epilogue: H = z*H + (1-z)*tanh(...); bf16 mirror at (Hb, ldhb);
// if dlinW != nullptr also computes yhat = relu(H_new) @ dlinW + dlinb
// (each 64-lane wave owns exactly one row: lane <-> 4 columns).
__global__ void k_gt_ep(const float* __restrict__ pbuf,
                        const float* __restrict__ bx2, const float* __restrict__ bh2,
                        const float* __restrict__ gz,
                        const float* __restrict__ x2, const float* __restrict__ ax2,
                        const float* __restrict__ Wx2,
                        float* __restrict__ H,
                        unsigned short* __restrict__ Hb, int ldhb,
                        const float* __restrict__ dlinW, const float* __restrict__ dlinb,
                        float* __restrict__ yhat)
{
    int i = blockIdx.x * 256 + threadIdx.x;  // < NN*256/4
    const float4* p = (const float4*)pbuf;
    const size_t S = (size_t)NN * HE / 4;
    float4 a = p[i];
#pragma unroll
    for (int z = 1; z < GT_NZ; z++) {
        float4 v = p[(size_t)z * S + i];
        a.x += v.x; a.y += v.y; a.z += v.z; a.w += v.w;
    }
    int row = i >> 6, c = (i & 63) << 2;
    if (Wx2) {
        float x0 = x2[2 * row], x1 = x2[2 * row + 1];
        float q0 = ax2[2 * row], q1 = ax2[2 * row + 1];
        float4 w00 = *(const float4*)&Wx2[c];
        float4 w01 = *(const float4*)&Wx2[HE + c];
        float4 w10 = *(const float4*)&Wx2[2 * HE + c];
        float4 w11 = *(const float4*)&Wx2[3 * HE + c];
        a.x += x0 * w00.x + x1 * w01.x + q0 * w10.x + q1 * w11.x;
        a.y += x0 * w00.y + x1 * w01.y + q0 * w10.y + q1 * w11.y;
        a.z += x0 * w00.z + x1 * w01.z + q0 * w10.z + q1 * w11.z;
        a.w += x0 * w00.w + x1 * w01.w + q0 * w10.w + q1 * w11.w;
    }
    float4 b0 = *(const float4*)&bx2[c];
    float4 b1 = *(const float4*)&bh2[c];
    size_t idx = (size_t)row * HE + c;
    float4 z = *(const float4*)&gz[idx];
    float4 h = *(const float4*)&H[idx];
    float4 o;
    o.x = z.x * h.x + (1.f - z.x) * tanhf(a.x + b0.x + b1.x);
    o.y = z.y * h.y + (1.f - z.y) * tanhf(a.y + b0.y + b1.y);
    o.z = z.z * h.z + (1.f - z.z) * tanhf(a.z + b0.z + b1.z);
    o.w = z.w * h.w + (1.f - z.w) * tanhf(a.w + b0.w + b1.w);
    *(float4*)&H[idx] = o;
    short4v sb;
    sb[0] = (short)f2bf(o.x); sb[1] = (short)f2bf(o.y);
    sb[2] = (short)f2bf(o.z); sb[3] = (short)f2bf(o.w);
    *(short4v*)&Hb[(size_t)row * ldhb + c] = sb;
    if (dlinW) {
        // fused declin: wave = one row, lane covers columns c..c+3
        float a0 = 0.f, a1 = 0.f;
        float ov[4] = {o.x, o.y, o.z, o.w};
#pragma unroll
        for (int j = 0; j < 4; j++) {
            float v = fmaxf(ov[j], 0.f);
            float2 b = *(const float2*)&dlinW[(c + j) * 2];
            a0 = fmaf(v, b.x, a0);
            a1 = fmaf(v, b.y, a1);
        }
        for (int off = 32; off > 0; off >>= 1) {
            a0 += __shfl_down(a0, off, 64);
            a1 += __shfl_down(a1, off, 64);
        }
        if ((threadIdx.x & 63) == 0) {
            yhat[2 * row] = a0 + dlinb[0];
            yhat[2 * row + 1] = a1 + dlinb[1];
        }
    }
}

// latent linear K-split (MFMA, relu on A)
__global__ __launch_bounds__(256) void k_lin_ks(
    const float* __restrict__ A, const float* __restrict__ B,
    float* __restrict__ pbuf)
{
    __shared__ __align__(16) unsigned short Ah[64][40], Al[64][40],
                                            Bh[64][40], Bl[64][40];
    int tid = threadIdx.x;
    int wid = tid >> 6, lane = tid & 63, lr = lane & 15, kg = lane >> 4;
    int m0 = blockIdx.x << 6;
    int n0 = blockIdx.y << 6;
    int lo = blockIdx.z << 5;  // 32 per slice
    float4v acc[4];
#pragma unroll
    for (int t = 0; t < 4; t++) acc[t] = (float4v){0.f, 0.f, 0.f, 0.f};
    mfma_seg<true>(Ah, Al, Bh, Bl, A + lo, HE, B + (size_t)lo * LT + n0, LT, 32,
                   m0, tid, wid, lr, kg, acc);
    float* p = pbuf + (size_t)blockIdx.z * NN * LT;
#pragma unroll
    for (int t = 0; t < 4; t++)
#pragma unroll
        for (int j = 0; j < 4; j++)
            p[(size_t)(m0 + (wid << 4) + (kg << 2) + j) * LT + n0 + (t << 4) + lr] =
                acc[t][j];
}

// writes zlat fp32 + bf16 mirror into xcat_b[:, 0:128]
__global__ void k_lin_ep(const float* __restrict__ pbuf,
                         const float* __restrict__ bias, float* __restrict__ out,
                         unsigned short* __restrict__ zb)
{
    int i = blockIdx.x * 256 + threadIdx.x;  // < NN*128/4
    const float4* p = (const float4*)pbuf;
    const size_t S = (size_t)NN * LT / 4;
    int row = i >> 5, c = (i & 31) << 2;
    float4 bb = *(const float4*)&bias[c];
    float4 s = make_float4(bb.x, bb.y, bb.z, bb.w);
#pragma unroll
    for (int z = 0; z < LIN_NZ; z++) {
        float4 v = p[z * S + i];
        s.x += v.x; s.y += v.y; s.z += v.z; s.w += v.w;
    }
    ((float4*)out)[i] = s;
    short4v sb;
    sb[0] = (short)f2bf(s.x); sb[1] = (short)f2bf(s.y);
    sb[2] = (short)f2bf(s.z); sb[3] = (short)f2bf(s.w);
    *(short4v*)&zb[(size_t)row * XC + c] = sb;
}

// fp32 -> bf16 mirror with output stride (for initial states)
__global__ void k_cvtb(const float* __restrict__ in, unsigned short* __restrict__ outb,
                       int ldo) {
    int i = blockIdx.x * 256 + threadIdx.x;
    int r = i >> 8, c = i & 255;
    outb[(size_t)r * ldo + c] = f2bf(in[i]);
}

extern "C" void kernel_launch(void* const* d_in, const int* in_sizes, int n_in,
                              void* d_out, int out_size, void* d_ws, size_t ws_size,
                              hipStream_t stream) {
    (void)in_sizes; (void)n_in; (void)out_size; (void)ws_size;
    const float* x_seq = (const float*)d_in[0];
    const int* ei = (const int*)d_in[1];
    const float* ews = (const float*)d_in[2];
    const float* h_enc_in = (const float*)d_in[3];
    const float* h_dec_in = (const float*)d_in[4];
    const float* encWx = (const float*)d_in[5];
    const float* encbx = (const float*)d_in[6];
    const float* encWh = (const float*)d_in[7];
    const float* encbh = (const float*)d_in[8];
    const float* elinW = (const float*)d_in[9];
    const float* elinb = (const float*)d_in[10];
    const float* decWx = (const float*)d_in[11];
    const float* decbx = (const float*)d_in[12];
    const float* decWh = (const float*)d_in[13];
    const float* decbh = (const float*)d_in[14];
    const float* dlinW = (const float*)d_in[15];
    const float* dlinb = (const float*)d_in[16];
    float* out = (float*)d_out;

    float* W = (float*)d_ws;
    float* h_enc = W; W += (size_t)NN * HE;
    float* h_dec = W; W += (size_t)NN * HE;
    float* aggh  = W; W += (size_t)NN * HE;
    float* hr    = W; W += (size_t)NN * HE;
    float* agghr = W; W += (size_t)NN * HE;
    float* gz    = W; W += (size_t)NN * HE;
    float* zlat  = W; W += (size_t)NN * LT;
    float* Y     = W; W += (size_t)NN * XC;
    float* yhat  = W; W += (size_t)NN * FIN;
    float* aggx2 = W; W += (size_t)NN * FIN;
    float* dinv_d = W; W += NN;
    unsigned short* Mb = (unsigned short*)W; W += (size_t)NN * NN / 2;
    float* pbuf  = W; W += (size_t)DMM_NZ * NN * XC;
    unsigned short* Hen_b = (unsigned short*)W; W += (size_t)NN * HE / 2;
    unsigned short* hr_b  = (unsigned short*)W; W += (size_t)NN * HE / 2;
    unsigned short* xcat_b = (unsigned short*)W; W += (size_t)NN * XC / 2;
    float* deg_all = W; W += (size_t)T_OBS * NN;
    int*   cnt_all = (int*)W; W += (size_t)T_OBS * NN;
    float* dinv_all = W; W += (size_t)T_OBS * NN;
    float* csr_nrm_all = W; W += (size_t)T_OBS * EE;
    float* aggx_all = W; W += (size_t)T_OBS * NN * FIN;
    int* roff_all = (int*)W; W += (size_t)T_OBS * (NN + 1) + 1;
    int* cur_all = (int*)W; W += (size_t)T_OBS * NN;
    int* csr_src_all = (int*)W; W += (size_t)T_OBS * EE;

    // ---- batched sparse prep ----
    hipMemsetAsync(deg_all, 0, sizeof(float) * T_OBS * NN * 2, stream);  // deg+cnt
    k_degcnt_lds<<<dim3(8, T_OBS), 256, 0, stream>>>(ei, ews, deg_all, cnt_all);
    k_scan_b<<<T_OBS, 256, 0, stream>>>(cnt_all, deg_all, roff_all, cur_all, dinv_all);
    k_scatter2_b<<<dim3(EE / 256, T_OBS), 256, 0, stream>>>(ei, ews, dinv_all, cur_all,
                                                            csr_src_all, csr_nrm_all);
    k_spmm2_b<<<dim3(NN / 256, T_OBS), 256, 0, stream>>>(roff_all, csr_src_all,
                                                         csr_nrm_all, x_seq, aggx_all);

    hipMemcpyAsync(h_enc, h_enc_in, sizeof(float) * NN * HE, hipMemcpyDeviceToDevice, stream);
    hipMemcpyAsync(h_dec, h_dec_in, sizeof(float) * NN * HE, hipMemcpyDeviceToDevice, stream);
    k_cvtb<<<NN * HE / 256, 256, 0, stream>>>(h_enc_in, Hen_b, HE);
    k_cvtb<<<NN * HE / 256, 256, 0, stream>>>(h_dec_in, xcat_b + LT, XC);

    for (int step = 0; step < T_OBS + PREDN - 1; ++step) {
        bool sparse = step < T_OBS;
        const float* xin;
        const float* aggx_s;
        const int* roff = roff_all + step * (NN + 1);
        const int* csr_src = csr_src_all + (size_t)step * EE;
        const float* csr_nrm = csr_nrm_all + (size_t)step * EE;
        if (sparse) {
            xin = x_seq + (size_t)step * NN * FIN;
            aggx_s = aggx_all + (size_t)step * NN * FIN;
        } else {
            k_ddeg<<<NN, 256, 0, stream>>>(yhat, dinv_d);
            k_dM2<<<NN, 256, 0, stream>>>(yhat, dinv_d, Mb, aggx2);
            xin = yhat;
            aggx_s = aggx2;
        }

        // ======= encoder GRU (x: F=2 via rank-2 epilogue, H: h_enc) =======
        if (sparse) {
            k_spmm_vb<HE, 64><<<NN / 4, 256, 0, stream>>>(roff, csr_src, csr_nrm,
                                                          Hen_b, aggh, HE);
        } else {
            k_dmm_mfb<HE><<<dim3(NN / 64, HE / 64, DMM_NZ), 256, 0, stream>>>(Mb, Hen_b, pbuf);
            k_redks<HE, DMM_NZ><<<NN * HE / 4 / 256, 256, 0, stream>>>(pbuf, aggh);
        }
        k_zr_ks<<<dim3(NN / 64, 8, ZR_NZ), 256, 0, stream>>>(xin, 0, aggx_s, h_enc, aggh,
                                                             FIN, HE, HE,
                                                             encWx, encWh, pbuf);
        k_zr_ep<<<NN * 512 / 4 / 256, 256, 0, stream>>>(pbuf, encbx, encbh, h_enc,
                                                        xin, aggx_s, encWx, gz, hr, hr_b);
        if (sparse) {
            k_spmm_vb<HE, 64><<<NN / 4, 256, 0, stream>>>(roff, csr_src, csr_nrm,
                                                          hr_b, agghr, HE);
        } else {
            k_dmm_mfb<HE><<<dim3(NN / 64, HE / 64, DMM_NZ), 256, 0, stream>>>(Mb, hr_b, pbuf);
            k_redks<HE, DMM_NZ><<<NN * HE / 4 / 256, 256, 0, stream>>>(pbuf, agghr);
        }
        k_gt_ks<<<dim3(NN / 64, 4, GT_NZ), 256, 0, stream>>>(xin, 0, aggx_s, hr, agghr,
                                                             FIN, HE, HE,
                                                             encWx + 4 * FIN * HE,
                                                             encWh + 4 * HE * HE, pbuf);
        k_gt_ep<<<NN * HE / 4 / 256, 256, 0, stream>>>(pbuf, encbx + 2 * HE,
                                                       encbh + 2 * HE, gz,
                                                       xin, aggx_s, encWx + 4 * FIN * HE,
                                                       h_enc, Hen_b, HE,
                                                       nullptr, nullptr, nullptr);
        k_lin_ks<<<dim3(NN / 64, 2, LIN_NZ), 256, 0, stream>>>(h_enc, elinW, pbuf);
        k_lin_ep<<<NN * LT / 4 / 256, 256, 0, stream>>>(pbuf, elinb, zlat, xcat_b);

        // ======= decoder GRU: combined agg of [zlat | h_dec] = xcat_b =======
        if (sparse) {
            k_spmm_vb<XC, 128><<<NN / 2, 256, 0, stream>>>(roff, csr_src, csr_nrm,
                                                           xcat_b, Y, XC);
        } else {
            k_dmm_mfb<XC><<<dim3(NN / 64, XC / 64, DMM_NZ), 256, 0, stream>>>(Mb, xcat_b, pbuf);
            k_redks<XC, DMM_NZ><<<NN * XC / 4 / 256, 256, 0, stream>>>(pbuf, Y);
        }
        k_zr_ks<<<dim3(NN / 64, 8, ZR_NZ), 256, 0, stream>>>(zlat, LT, Y, h_dec, Y + LT,
                                                             XC, HE, XC,
                                                             decWx, decWh, pbuf);
        k_zr_ep<<<NN * 512 / 4 / 256, 256, 0, stream>>>(pbuf, decbx, decbh, h_dec,
                                                        nullptr, nullptr, nullptr,
                                                        gz, hr, hr_b);
        if (sparse) {
            k_spmm_vb<HE, 64><<<NN / 4, 256, 0, stream>>>(roff, csr_src, csr_nrm,
                                                          hr_b, agghr, HE);
        } else {
            k_dmm_mfb<HE><<<dim3(NN / 64, HE / 64, DMM_NZ), 256, 0, stream>>>(Mb, hr_b, pbuf);
            k_redks<HE, DMM_NZ><<<NN * HE / 4 / 256, 256, 0, stream>>>(pbuf, agghr);
        }
        k_gt_ks<<<dim3(NN / 64, 4, GT_NZ), 256, 0, stream>>>(zlat, LT, Y, hr, agghr,
                                                             XC, HE, HE,
                                                             decWx + 4 * LT * HE,
                                                             decWh + 4 * HE * HE, pbuf);
        k_gt_ep<<<NN * HE / 4 / 256, 256, 0, stream>>>(pbuf, decbx + 2 * HE,
                                                       decbh + 2 * HE, gz,
                                                       nullptr, nullptr, nullptr,
                                                       h_dec, xcat_b + LT, XC,
                                                       dlinW, dlinb, yhat);

        if (step >= T_OBS - 1) {
            hipMemcpyAsync(out + (size_t)(step - (T_OBS - 1)) * NN * FIN, yhat,
                           sizeof(float) * NN * FIN, hipMemcpyDeviceToDevice, stream);
        }
    }
}